// Round 12
// baseline (15544.679 us; speedup 1.0000x reference)
//
#include <hip/hip_runtime.h>

// AlphatRNN B=128,T=512,D=256,H=1024,L=2,O=1 — bf16 MFMA persistent kernel, R12.
// R12 = R11 (flags + swapped layout + dedup, 14.1ms) with LAYER OVERLAP:
// waves 0-3 = layer-0 engine (B chain), waves 4-7 = layer-1 engine (C+D chain).
// No __syncthreads in the loop; each chain has private LDS reduce planes and
// LDS-atomic sub-barriers (4-wave). Layer-0 runs 1-2 steps ahead (h0/s1 parity
// double-buffers + cross-chain throttle flags bound the lead). Each chain pays
// ~1 flag-RTT/step and they overlap -> serial chain ~3x shorter than R11.

typedef unsigned short u16;
typedef unsigned long long u64;
typedef __attribute__((ext_vector_type(8))) short short8;
typedef __attribute__((ext_vector_type(4))) float f32x4;

#define NB   128
#define TT   512
#define DD   256
#define HH   1024
#define NWG  256
#define NTHR 512
#define SPAN (NB * HH)

// ---- ws layout (bytes) ----
#define S0_OFF  0u          // bf16 [2][128][1024] s0 parity
#define S1_OFF  524288u     // bf16 [2][128][1024] s1 parity
#define H0_OFF  1048576u    // bf16 [2][128][1024] h0 parity
#define FL_OFF  1572864u    // fB/fC/fD: 3 x [8 mg][32 wgl] x 64 B = 48 KB
#define W_OFF   1622016u    // bf16 weights: 6x[1024][1024], then [1024][256]x2
#define NBIG    6291456u

__device__ __forceinline__ u16 f2bf(float f) {
    unsigned u = __builtin_bit_cast(unsigned, f);
    return (u16)((u + 0x7fffu + ((u >> 16) & 1u)) >> 16);
}
__device__ __forceinline__ u64 agent_load64(const u64* p) {
    return __hip_atomic_load(p, __ATOMIC_RELAXED, __HIP_MEMORY_SCOPE_AGENT);
}
__device__ __forceinline__ void agent_store64(u64* p, u64 v) {
    __hip_atomic_store(p, v, __ATOMIC_RELAXED, __HIP_MEMORY_SCOPE_AGENT);
}

// 4-wave sub-barrier on an LDS counter (monotonic; pass*4 target). Lane0 of
// each wave adds; all lanes spin (LDS broadcast). ACQ_REL orders LDS red data.
__device__ __forceinline__ void cbar(unsigned* c, unsigned& pass, int tid)
{
    ++pass;
    const unsigned tgt = pass * 4u;
    if ((tid & 63) == 0)
        __hip_atomic_fetch_add(c, 1u, __ATOMIC_ACQ_REL, __HIP_MEMORY_SCOPE_WORKGROUP);
    while (__hip_atomic_load(c, __ATOMIC_ACQUIRE, __HIP_MEMORY_SCOPE_WORKGROUP) < tgt)
        __builtin_amdgcn_s_sleep(1);
}

// Consumer wait: lanes 0..31 of the calling wave poll the 32 group flags.
__device__ __forceinline__ void flag_wait(unsigned* f, unsigned val, int tid)
{
    if ((tid & 63) < 32)
        while (__hip_atomic_load(f + (tid & 63) * 16, __ATOMIC_RELAXED,
                                 __HIP_MEMORY_SCOPE_AGENT) < val)
            __builtin_amdgcn_s_sleep(1);
}

// State frags, one K-quarter (256 k): lane(lrow,lkg) row m0+lrow,
// k = cw*256 + s*32 + lkg*8, s=0..7. sc1 loads from published span.
__device__ __forceinline__ void load_frags(short8* fr, const u16* base,
                                           int row, int cw, int lkg)
{
    const u16* sp = base + ((size_t)row << 10) + cw * 256 + lkg * 8;
    #pragma unroll
    for (int s = 0; s < 8; ++s) {
        union { short8 v; u64 q[2]; } u_;
        u_.q[0] = agent_load64((const u64*)(sp + s * 32));
        u_.q[1] = agent_load64((const u64*)(sp + s * 32 + 4));
        fr[s] = u_.v;
    }
}

// a0/a1 += W[wr0/wr1, K-quarter] (x) S(frags), swapped operands.
__device__ __forceinline__ void mm2(f32x4& a0, f32x4& a1, const short8* fr,
                                    const u16* W, int wr0, int wr1, int cw, int lkg)
{
    const u16* wp0 = W + ((size_t)wr0 << 10) + cw * 256 + lkg * 8;
    const u16* wp1 = W + ((size_t)wr1 << 10) + cw * 256 + lkg * 8;
    #pragma unroll
    for (int s = 0; s < 8; ++s) {
        a0 = __builtin_amdgcn_mfma_f32_16x16x32_bf16(
            *(const short8*)(wp0 + s * 32), fr[s], a0, 0, 0, 0);
        a1 = __builtin_amdgcn_mfma_f32_16x16x32_bf16(
            *(const short8*)(wp1 + s * 32), fr[s], a1, 0, 0, 0);
    }
}

// a0/a1 += Wx[wr0/wr1, K-quarter of 256] (x) x_row(fp32->bf16), swapped.
__device__ __forceinline__ void mmx2(f32x4& a0, f32x4& a1, const float* xrow,
                                     const u16* W, int wr0, int wr1, int cw, int lkg)
{
    #pragma unroll
    for (int s = 0; s < 2; ++s) {
        const float* p = xrow + cw * 64 + s * 32 + lkg * 8;
        float4 a = *(const float4*)p;
        float4 b = *(const float4*)(p + 4);
        short8 v;
        v[0]=(short)f2bf(a.x); v[1]=(short)f2bf(a.y); v[2]=(short)f2bf(a.z); v[3]=(short)f2bf(a.w);
        v[4]=(short)f2bf(b.x); v[5]=(short)f2bf(b.y); v[6]=(short)f2bf(b.z); v[7]=(short)f2bf(b.w);
        const u16* wp0 = W + ((size_t)wr0 << 8) + cw * 64 + s * 32 + lkg * 8;
        const u16* wp1 = W + ((size_t)wr1 << 8) + cw * 64 + s * 32 + lkg * 8;
        a0 = __builtin_amdgcn_mfma_f32_16x16x32_bf16(*(const short8*)wp0, v, a0, 0, 0, 0);
        a1 = __builtin_amdgcn_mfma_f32_16x16x32_bf16(*(const short8*)wp1, v, a1, 0, 0, 0);
    }
}

// reduce planes: [q][comp][nt][cw][lane], 4B lane stride, conflict-free.
__device__ __forceinline__ void red_put(float (*red)[4][2][4][64], int q,
                                        f32x4 a0, f32x4 a1, int cw, int lane)
{
    #pragma unroll
    for (int c = 0; c < 4; ++c) {
        red[q][c][0][cw][lane] = a0[c];
        red[q][c][1][cw][lane] = a1[c];
    }
}
__device__ __forceinline__ f32x4 red_get(float (*red)[4][2][4][64], int q,
                                         int nt, int lane)
{
    f32x4 v = {0.f, 0.f, 0.f, 0.f};
    #pragma unroll
    for (int j = 0; j < 4; ++j)
        #pragma unroll
        for (int c = 0; c < 4; ++c) v[c] += red[q][c][nt][j][lane];
    return v;
}

__device__ __forceinline__ u64 pack4(float a, float b, float c, float d)
{
    return (u64)f2bf(a) | ((u64)f2bf(b) << 16) | ((u64)f2bf(c) << 32)
         | ((u64)f2bf(d) << 48);
}

__global__ void conv_weights(const float* Uas0, const float* Whh0, const float* Wax1,
                             const float* Uas1, const float* Wih1, const float* Whh1,
                             const float* Wax0, const float* Wih0, u16* dst)
{
    for (size_t i = (size_t)blockIdx.x * blockDim.x + threadIdx.x; i < 6815744u;
         i += (size_t)gridDim.x * blockDim.x) {
        const float* src; size_t off;
        if (i < NBIG) {
            int seg = (int)(i >> 20); off = i & 1048575u;
            src = seg == 0 ? Uas0 : seg == 1 ? Whh0 : seg == 2 ? Wax1
                : seg == 3 ? Uas1 : seg == 4 ? Wih1 : Whh1;
        } else {
            size_t j = i - NBIG; off = j & 262143u;
            src = (j >> 18) ? Wih0 : Wax0;
        }
        dst[i] = f2bf(src[off]);
    }
}

extern "C" __global__ void __launch_bounds__(NTHR, 1)
alphat_mfma(const float* __restrict__ x,
            const u16* __restrict__ wUas0, const u16* __restrict__ wWhh0,
            const u16* __restrict__ wWax1, const u16* __restrict__ wUas1,
            const u16* __restrict__ wWih1, const u16* __restrict__ wWhh1,
            const u16* __restrict__ wWax0, const u16* __restrict__ wWih0,
            const float* __restrict__ ba0, const float* __restrict__ bh0,
            const float* __restrict__ ba1, const float* __restrict__ bh1,
            const float* __restrict__ fcW, const float* __restrict__ fcb,
            float* __restrict__ out,
            u16* s0b, u16* s1b, u16* h0b, unsigned* flags)
{
    __shared__ float red0[2][4][2][4][64];   // 16 KB: layer-0 planes (q=0:B, q=1:alpha0)
    __shared__ float red1[1][4][2][4][64];   //  8 KB: layer-1 plane (C then D)
    __shared__ unsigned cc[2];               // sub-barrier counters

    const int tid  = threadIdx.x;
    const int wv   = tid >> 6;
    const int lane = tid & 63;
    const int lrow = lane & 15;
    const int lkg  = lane >> 4;

    const int wg  = blockIdx.x;
    const int ng  = (wg & 7) * 4 + ((wg >> 3) & 3);
    const int mg  = wg >> 5;
    const int wgl = wg & 31;
    const int m0  = mg * 16;
    const int n0  = ng * 32;

    unsigned* fB = flags + (size_t)mg * 512;
    unsigned* fC = flags + 4096  + (size_t)mg * 512;
    unsigned* fD = flags + 8192  + (size_t)mg * 512;

    const int wr0  = n0 + lrow;
    const int wr1  = n0 + 16 + lrow;
    const int arow = m0 + lrow;

    if (tid < 2) cc[tid] = 0;
    __syncthreads();                 // only WG-wide barrier (prologue)

    const f32x4 zf = {0.f, 0.f, 0.f, 0.f};

    if (wv < 4) {
        // ================= layer-0 engine (B chain), waves 0-3 ================
        const int cw  = wv;
        const bool own = (cw < 2);
        const int nb  = n0 + cw * 16 + lkg * 4;       // owner cols (cw<2)
        float4 vba0 = {0,0,0,0}, vbh0 = {0,0,0,0};
        if (own) { vba0 = *(const float4*)(ba0 + nb); vbh0 = *(const float4*)(bh0 + nb); }

        float h0l[4] = {0,0,0,0}, s0l[4] = {0,0,0,0};
        unsigned pass = 0;

        short8 frags[8];
        #pragma unroll
        for (int s = 0; s < 8; ++s)
            #pragma unroll
            for (int i = 0; i < 8; ++i) frags[s][i] = 0;
        const float* xbase = x + (size_t)arow * (TT * DD);
        f32x4 pBx0 = zf, pBx1 = zf, pAx0 = zf, pAx1 = zf;
        mmx2(pBx0, pBx1, xbase + 0 * DD, wWih0, wr0, wr1, cw, lkg);
        mmx2(pAx0, pAx1, xbase + 1 * DD, wWax0, wr0, wr1, cw, lkg);

        for (int t = 0; t < TT; ++t) {
            u16* h0cur = h0b + (t & 1) * SPAN;
            u16* s0nxt = s0b + ((t + 1) & 1) * SPAN;

            f32x4 a0 = pBx0, a1 = pBx1, q0 = pAx0, q1 = pAx1;
            mm2(a0, a1, frags, wWhh0, wr0, wr1, cw, lkg);
            mm2(q0, q1, frags, wUas0, wr0, wr1, cw, lkg);
            red_put(red0, 0, a0, a1, cw, lane);
            red_put(red0, 1, q0, q1, cw, lane);
            cbar(&cc[0], pass, tid);
            if (own) {
                f32x4 acc = red_get(red0, 0, cw, lane);
                f32x4 pA  = red_get(red0, 1, cw, lane);
                float hb[4];
                #pragma unroll
                for (int r = 0; r < 4; ++r) {
                    hb[r] = tanhf(acc[r] + ((const float*)&vbh0)[r]);
                    h0l[r] = hb[r];
                }
                agent_store64((u64*)(h0cur + (size_t)(m0 + lrow) * HH + nb),
                              pack4(hb[0], hb[1], hb[2], hb[3]));
                if (t + 1 < TT) {
                    float sb[4];
                    #pragma unroll
                    for (int r = 0; r < 4; ++r) {
                        float al = 1.f / (1.f + __expf(-(pA[r] + ((const float*)&vba0)[r])));
                        sb[r] = al * hb[r] + (1.f - al) * s0l[r];
                        s0l[r] = sb[r];
                    }
                    agent_store64((u64*)(s0nxt + (size_t)(m0 + lrow) * HH + nb),
                                  pack4(sb[0], sb[1], sb[2], sb[3]));
                }
                asm volatile("s_waitcnt vmcnt(0)" ::: "memory");
            }
            cbar(&cc[0], pass, tid);   // all owner stores drained; red reads done
            if (tid == 0)
                __hip_atomic_store(fB + wgl * 16, (unsigned)(t + 1),
                                   __ATOMIC_RELEASE, __HIP_MEMORY_SCOPE_AGENT);

            // non-critical tail: x partials, group waits, next frags
            if (t + 1 < TT) {
                pBx0 = zf; pBx1 = zf;
                mmx2(pBx0, pBx1, xbase + (size_t)(t + 1) * DD, wWih0, wr0, wr1, cw, lkg);
            }
            if (t + 2 < TT) {
                pAx0 = zf; pAx1 = zf;
                mmx2(pAx0, pAx1, xbase + (size_t)(t + 2) * DD, wWax0, wr0, wr1, cw, lkg);
            }
            if (t + 1 < TT) {
                flag_wait(fB, (unsigned)(t + 1), tid);      // s0(t+1) all published
                load_frags(frags, s0nxt, arow, cw, lkg);
                // throttle: B(t+1) publishes h0[(t+1)&1], overwriting h0(t-1);
                // C(t-1) readers are covered once fC >= t.
                if (t >= 1) flag_wait(fC, (unsigned)t, tid);
            }
        }

        // epilogue: h0/s0 outputs
        if (own) {
            const size_t HIDB = NB, SMOB = NB + 2 * (size_t)SPAN;
            const size_t o = (size_t)(m0 + lrow) * HH + nb;
            *(float4*)(out + HIDB + o) = make_float4(h0l[0], h0l[1], h0l[2], h0l[3]);
            *(float4*)(out + SMOB + o) = make_float4(s0l[0], s0l[1], s0l[2], s0l[3]);
        }
    } else {
        // ================= layer-1 engine (C+D chain), waves 4-7 ==============
        const int cw  = wv - 4;
        const bool own = (cw < 2);
        const int nb  = n0 + cw * 16 + lkg * 4;
        float4 vba1 = {0,0,0,0}, vbh1 = {0,0,0,0};
        if (own) { vba1 = *(const float4*)(ba1 + nb); vbh1 = *(const float4*)(bh1 + nb); }

        float h1l[4] = {0,0,0,0}, s1l[4] = {0,0,0,0};
        unsigned pass = 0;
        f32x4 pC10 = zf, pC11 = zf, pD10 = zf, pD11 = zf;

        for (int t = 0; t < TT; ++t) {
            u16* h0cur = h0b + (t & 1) * SPAN;
            u16* s1cur = s1b + (t & 1) * SPAN;

            // ---- C: wait h0(t); alpha1; publish s1(t) ----
            flag_wait(fB, (unsigned)(t + 1), tid);
            short8 fh[8];
            load_frags(fh, h0cur, arow, cw, lkg);
            f32x4 c0 = pC10, c1 = pC11;
            mm2(c0, c1, fh, wWax1, wr0, wr1, cw, lkg);
            pD10 = zf; pD11 = zf;
            mm2(pD10, pD11, fh, wWih1, wr0, wr1, cw, lkg);
            red_put(red1, 0, c0, c1, cw, lane);
            cbar(&cc[1], pass, tid);
            if (own) {
                f32x4 acc = red_get(red1, 0, cw, lane);
                float sb[4];
                #pragma unroll
                for (int r = 0; r < 4; ++r) {
                    float al = 1.f / (1.f + __expf(-(acc[r] + ((const float*)&vba1)[r])));
                    sb[r] = al * h1l[r] + (1.f - al) * s1l[r];
                    s1l[r] = sb[r];
                }
                agent_store64((u64*)(s1cur + (size_t)(m0 + lrow) * HH + nb),
                              pack4(sb[0], sb[1], sb[2], sb[3]));
                asm volatile("s_waitcnt vmcnt(0)" ::: "memory");
            }
            cbar(&cc[1], pass, tid);
            if (tid == 256)
                __hip_atomic_store(fC + wgl * 16, (unsigned)(t + 1),
                                   __ATOMIC_RELEASE, __HIP_MEMORY_SCOPE_AGENT);

            // ---- D: wait s1(t); h1; pC1 for C(t+1) ----
            flag_wait(fC, (unsigned)(t + 1), tid);
            short8 fs1[8];
            load_frags(fs1, s1cur, arow, cw, lkg);
            f32x4 d0 = pD10, d1 = pD11;
            mm2(d0, d1, fs1, wWhh1, wr0, wr1, cw, lkg);
            pC10 = zf; pC11 = zf;
            mm2(pC10, pC11, fs1, wUas1, wr0, wr1, cw, lkg);
            red_put(red1, 0, d0, d1, cw, lane);
            cbar(&cc[1], pass, tid);
            if (own) {
                f32x4 acc = red_get(red1, 0, cw, lane);
                #pragma unroll
                for (int r = 0; r < 4; ++r)
                    h1l[r] = tanhf(acc[r] + ((const float*)&vbh1)[r]);
            }
            cbar(&cc[1], pass, tid);   // mfma (s1 frag consumption) complete in all waves
            if (tid == 256)
                __hip_atomic_store(fD + wgl * 16, (unsigned)(t + 1),
                                   __ATOMIC_RELEASE, __HIP_MEMORY_SCOPE_AGENT);

            // throttle: C(t+1) publishes s1[(t+1)&1], overwriting s1(t-1);
            // D(t-1) readers covered once fD >= t.
            if (t >= 1 && t + 1 < TT) flag_wait(fD, (unsigned)t, tid);
        }

        // epilogue: h1/s1 outputs + fc
        if (own) {
            const size_t HIDB = NB, SMOB = NB + 2 * (size_t)SPAN;
            const size_t o = (size_t)(m0 + lrow) * HH + nb;
            *(float4*)(out + HIDB + SPAN + o) = make_float4(h1l[0], h1l[1], h1l[2], h1l[3]);
            *(float4*)(out + SMOB + SPAN + o) = make_float4(s1l[0], s1l[1], s1l[2], s1l[3]);

            const float4 w4 = *(const float4*)(fcW + nb);
            float v = h1l[0] * w4.x + h1l[1] * w4.y + h1l[2] * w4.z + h1l[3] * w4.w;
            v += __shfl_xor(v, 16);
            v += __shfl_xor(v, 32);
            if (lane < 16) {
                if (ng == 0 && cw == 0) v += fcb[0];
                atomicAdd(out + m0 + lane, v);
            }
        }
    }
}

extern "C" void kernel_launch(void* const* d_in, const int* in_sizes, int n_in,
                              void* d_out, int out_size, void* d_ws, size_t ws_size,
                              hipStream_t stream)
{
    const float* x    = (const float*)d_in[0];
    const float* Wax0 = (const float*)d_in[1];
    const float* Uas0 = (const float*)d_in[2];
    const float* ba0  = (const float*)d_in[3];
    const float* Wih0 = (const float*)d_in[4];
    const float* Whh0 = (const float*)d_in[5];
    const float* bh0  = (const float*)d_in[6];
    const float* Wax1 = (const float*)d_in[7];
    const float* Uas1 = (const float*)d_in[8];
    const float* ba1  = (const float*)d_in[9];
    const float* Wih1 = (const float*)d_in[10];
    const float* Whh1 = (const float*)d_in[11];
    const float* bh1  = (const float*)d_in[12];
    const float* fcW  = (const float*)d_in[13];
    const float* fcb  = (const float*)d_in[14];
    float* out = (float*)d_out;

    char* ws = (char*)d_ws;
    u16* s0b = (u16*)(ws + S0_OFF);
    u16* s1b = (u16*)(ws + S1_OFF);
    u16* h0b = (u16*)(ws + H0_OFF);
    unsigned* flags = (unsigned*)(ws + FL_OFF);
    u16* wbase = (u16*)(ws + W_OFF);
    u16* wUas0 = wbase + 0 * 1048576;
    u16* wWhh0 = wbase + 1 * 1048576;
    u16* wWax1 = wbase + 2 * 1048576;
    u16* wUas1 = wbase + 3 * 1048576;
    u16* wWih1 = wbase + 4 * 1048576;
    u16* wWhh1 = wbase + 5 * 1048576;
    u16* wWax0 = wbase + 6 * 1048576;
    u16* wWih0 = wbase + 6 * 1048576 + 262144;

    hipMemsetAsync(d_ws, 0, W_OFF, stream);
    hipMemsetAsync(d_out, 0, (size_t)out_size * sizeof(float), stream);

    conv_weights<<<dim3(1024), dim3(256), 0, stream>>>(
        Uas0, Whh0, Wax1, Uas1, Wih1, Whh1, Wax0, Wih0, wbase);

    alphat_mfma<<<dim3(NWG), dim3(NTHR), 0, stream>>>(
        x, wUas0, wWhh0, wWax1, wUas1, wWih1, wWhh1, wWax0, wWih0,
        ba0, bh0, ba1, bh1, fcW, fcb, out, s0b, s1b, h0b, flags);
}

// Round 14
// 10342.488 us; speedup vs baseline: 1.5030x; 1.5030x over previous
//
#include <hip/hip_runtime.h>

// AlphatRNN B=128,T=512,D=256,H=1024,L=2,O=1 — bf16 MFMA persistent kernel, R14.
// R14 = R13's two-pool layer split made RESIDENCY-SAFE: 256 WGs total (proven
// co-resident config), blocks 0-127 = layer-0 pool (B chain, 1 exchange/step),
// blocks 128-255 = layer-1 pool (C+D, 1 serial exchange/step). WG tile 16x64
// (4 n-tiles per wave, 8 K-eighth waves, dedup'd state reads); sync groups of
// 16 WGs (fewer stragglers). h0 flows through a 32-step ring (8MB) so L1's
// h0-wait is pre-satisfied; pD1 GEMM computed inside the fC wait window.
// Flags monotonic, 64B-padded; all WAR windows span >=1 flag epoch (proofs in
// comments). Math identical to R11 (passing).

typedef unsigned short u16;
typedef unsigned long long u64;
typedef __attribute__((ext_vector_type(8))) short short8;
typedef __attribute__((ext_vector_type(4))) float f32x4;

#define NB   128
#define TT   512
#define DD   256
#define HH   1024
#define NTHR 512
#define SPAN (NB * HH)
#define RING 32
#define GS   16

// ---- ws layout (bytes) ----
#define S0_OFF  0u          // bf16 [2][128][1024] s0 parity
#define S1_OFF  524288u     // bf16 [2][128][1024] s1 parity
#define H0_OFF  1048576u    // bf16 [RING][128][1024] = 8 MB h0 ring
#define FL_OFF  9437184u    // fB/fC/fD: 3 x [8 mg][16 wgl] x 64 B = 24 KB
#define W_OFF   9486336u    // bf16 weights: 6x[1024][1024], then [1024][256]x2
#define NBIG    6291456u

__device__ __forceinline__ u16 f2bf(float f) {
    unsigned u = __builtin_bit_cast(unsigned, f);
    return (u16)((u + 0x7fffu + ((u >> 16) & 1u)) >> 16);
}
__device__ __forceinline__ u64 agent_load64(const u64* p) {
    return __hip_atomic_load(p, __ATOMIC_RELAXED, __HIP_MEMORY_SCOPE_AGENT);
}
__device__ __forceinline__ void agent_store64(u64* p, u64 v) {
    __hip_atomic_store(p, v, __ATOMIC_RELAXED, __HIP_MEMORY_SCOPE_AGENT);
}

// flag set: __syncthreads drains every wave's sc1 stores (compiler emits
// vmcnt(0) before s_barrier), then tid0 release-stores the step value.
__device__ __forceinline__ void flag_set(unsigned* f, int wgl, unsigned val, int tid)
{
    __syncthreads();
    if (tid == 0)
        __hip_atomic_store(f + wgl * 16, val, __ATOMIC_RELEASE,
                           __HIP_MEMORY_SCOPE_AGENT);
}
// consumer: lanes 0..15 (wave 0) poll the 16 group flags in parallel.
__device__ __forceinline__ void flag_wait(unsigned* f, unsigned val, int tid)
{
    if (tid < GS)
        while (__hip_atomic_load(f + tid * 16, __ATOMIC_RELAXED,
                                 __HIP_MEMORY_SCOPE_AGENT) < val)
            __builtin_amdgcn_s_sleep(1);
    __syncthreads();
}

// state frags, one K-EIGHTH (128 k): lane(lrow,lkg) reads row m0+lrow,
// k = wv*128 + s*32 + lkg*8, s=0..3. sc1 loads from a published span.
__device__ __forceinline__ void load_frags(short8* fr, const u16* base,
                                           int row, int wv, int lkg)
{
    const u16* sp = base + ((size_t)row << 10) + wv * 128 + lkg * 8;
    #pragma unroll
    for (int s = 0; s < 4; ++s) {
        union { short8 v; u64 q[2]; } u_;
        u_.q[0] = agent_load64((const u64*)(sp + s * 32));
        u_.q[1] = agent_load64((const u64*)(sp + s * 32 + 4));
        fr[s] = u_.v;
    }
}

// a[nt] += W[n0+nt*16+lrow, K-eighth] (x) S(frags), swapped operands
// (D rows = W rows = H-cols, D cols = batch). 16 mfma per call.
__device__ __forceinline__ void mm4(f32x4* a, const short8* fr, const u16* W,
                                    int n0, int lrow, int wv, int lkg)
{
    #pragma unroll
    for (int nt = 0; nt < 4; ++nt) {
        const u16* wp = W + ((size_t)(n0 + nt * 16 + lrow) << 10) + wv * 128 + lkg * 8;
        #pragma unroll
        for (int s = 0; s < 4; ++s)
            a[nt] = __builtin_amdgcn_mfma_f32_16x16x32_bf16(
                *(const short8*)(wp + s * 32), fr[s], a[nt], 0, 0, 0);
    }
}

// a[nt] += Wx[n0+nt*16+lrow, K-eighth of 256] (x) x_row(fp32->bf16), swapped.
__device__ __forceinline__ void mmx4(f32x4* a, const float* xrow, const u16* W,
                                     int n0, int lrow, int wv, int lkg)
{
    const float* p = xrow + wv * 32 + lkg * 8;
    float4 A = *(const float4*)p;
    float4 B = *(const float4*)(p + 4);
    short8 v;
    v[0]=(short)f2bf(A.x); v[1]=(short)f2bf(A.y); v[2]=(short)f2bf(A.z); v[3]=(short)f2bf(A.w);
    v[4]=(short)f2bf(B.x); v[5]=(short)f2bf(B.y); v[6]=(short)f2bf(B.z); v[7]=(short)f2bf(B.w);
    #pragma unroll
    for (int nt = 0; nt < 4; ++nt) {
        const u16* wp = W + ((size_t)(n0 + nt * 16 + lrow) << 8) + wv * 32 + lkg * 8;
        a[nt] = __builtin_amdgcn_mfma_f32_16x16x32_bf16(
            *(const short8*)wp, v, a[nt], 0, 0, 0);
    }
}

// 32KB reduce plane [comp][nt][wave][lane]: 4B lane stride, conflict-free.
__device__ __forceinline__ void red_put(float (*red)[4][8][64], const f32x4* a,
                                        int wv, int lane)
{
    #pragma unroll
    for (int nt = 0; nt < 4; ++nt)
        #pragma unroll
        for (int c = 0; c < 4; ++c) red[c][nt][wv][lane] = a[nt][c];
}
__device__ __forceinline__ f32x4 red_get(float (*red)[4][8][64], int nt, int lane)
{
    f32x4 v = {0.f, 0.f, 0.f, 0.f};
    #pragma unroll
    for (int j = 0; j < 8; ++j)
        #pragma unroll
        for (int c = 0; c < 4; ++c) v[c] += red[c][nt][j][lane];
    return v;
}

__device__ __forceinline__ u64 pack4(float a, float b, float c, float d)
{
    return (u64)f2bf(a) | ((u64)f2bf(b) << 16) | ((u64)f2bf(c) << 32)
         | ((u64)f2bf(d) << 48);
}

__global__ void conv_weights(const float* Uas0, const float* Whh0, const float* Wax1,
                             const float* Uas1, const float* Wih1, const float* Whh1,
                             const float* Wax0, const float* Wih0, u16* dst)
{
    for (size_t i = (size_t)blockIdx.x * blockDim.x + threadIdx.x; i < 6815744u;
         i += (size_t)gridDim.x * blockDim.x) {
        const float* src; size_t off;
        if (i < NBIG) {
            int seg = (int)(i >> 20); off = i & 1048575u;
            src = seg == 0 ? Uas0 : seg == 1 ? Whh0 : seg == 2 ? Wax1
                : seg == 3 ? Uas1 : seg == 4 ? Wih1 : Whh1;
        } else {
            size_t j = i - NBIG; off = j & 262143u;
            src = (j >> 18) ? Wih0 : Wax0;
        }
        dst[i] = f2bf(src[off]);
    }
}

extern "C" __global__ void __launch_bounds__(NTHR, 1)
alphat_mfma(const float* __restrict__ x,
            const u16* __restrict__ wUas0, const u16* __restrict__ wWhh0,
            const u16* __restrict__ wWax1, const u16* __restrict__ wUas1,
            const u16* __restrict__ wWih1, const u16* __restrict__ wWhh1,
            const u16* __restrict__ wWax0, const u16* __restrict__ wWih0,
            const float* __restrict__ ba0, const float* __restrict__ bh0,
            const float* __restrict__ ba1, const float* __restrict__ bh1,
            const float* __restrict__ fcW, const float* __restrict__ fcb,
            float* __restrict__ out,
            u16* s0b, u16* s1b, u16* h0r, unsigned* flags)
{
    __shared__ float red[4][4][8][64];   // 32 KB, one plane set (serial reuse)

    const int tid  = threadIdx.x;
    const int wv   = tid >> 6;           // K-eighth; waves 0-3 own n-tiles 0-3
    const int lane = tid & 63;
    const int lrow = lane & 15;
    const int lkg  = lane >> 4;

    const bool isL0 = (blockIdx.x < 128);
    const int wg  = isL0 ? blockIdx.x : (blockIdx.x - 128);
    const int ngg = (wg & 7) * 2 + ((wg >> 3) & 1);   // same-XCD pairs share cols
    const int mg  = wg >> 4;             // sync group = batch row-block
    const int wgl = wg & 15;
    const int m0  = mg * 16;
    const int n0  = ngg * 64;

    unsigned* fB = flags + (size_t)mg * 256;          // [16] x 16 dwords
    unsigned* fC = flags + 2048 + (size_t)mg * 256;
    unsigned* fD = flags + 4096 + (size_t)mg * 256;

    const int arow = m0 + lrow;
    const bool own = (wv < 4);
    const int nb   = n0 + (wv & 3) * 16 + lkg * 4;    // owner cols (wv<4)

    const f32x4 zf = {0.f, 0.f, 0.f, 0.f};
    const size_t HIDB = NB, SMOB = NB + 2 * (size_t)SPAN;

    if (isL0) {
        // ================== layer-0 pool: B chain (1 exchange/step) ==========
        float4 vba0 = {0,0,0,0}, vbh0 = {0,0,0,0};
        if (own) { vba0 = *(const float4*)(ba0 + nb); vbh0 = *(const float4*)(bh0 + nb); }
        float h0l[4] = {0,0,0,0}, s0l[4] = {0,0,0,0};

        short8 frags[4];
        #pragma unroll
        for (int s = 0; s < 4; ++s)
            #pragma unroll
            for (int i = 0; i < 8; ++i) frags[s][i] = 0;
        const float* xbase = x + (size_t)arow * (TT * DD);
        f32x4 pBx[4], pAx[4];
        #pragma unroll
        for (int nt = 0; nt < 4; ++nt) { pBx[nt] = zf; pAx[nt] = zf; }
        mmx4(pBx, xbase + 0 * DD, wWih0, n0, lrow, wv, lkg);   // Wih0 x_0
        mmx4(pAx, xbase + 1 * DD, wWax0, n0, lrow, wv, lkg);   // Wax0 x_1

        for (int t = 0; t < TT; ++t) {
            u16* h0cur = h0r + (size_t)(t & (RING - 1)) * SPAN;
            u16* s0nxt = s0b + ((t + 1) & 1) * SPAN;

            // ring WAR: overwriting slot holds h0(t-32); C(t-32) readers done
            // iff fC >= t-31 (fC set after C's fh loads).
            if (t >= RING) flag_wait(fC, (unsigned)(t - RING + 1), tid);

            f32x4 acc[4], pA[4];
            #pragma unroll
            for (int nt = 0; nt < 4; ++nt) { acc[nt] = pBx[nt]; pA[nt] = pAx[nt]; }
            mm4(acc, frags, wWhh0, n0, lrow, wv, lkg);
            mm4(pA,  frags, wUas0, n0, lrow, wv, lkg);

            // two sequential reduces through one 32KB plane
            red_put(red, acc, wv, lane);
            __syncthreads();
            f32x4 hsum = zf;
            if (own) hsum = red_get(red, wv, lane);
            __syncthreads();
            red_put(red, pA, wv, lane);
            __syncthreads();
            if (own) {
                f32x4 asum = red_get(red, wv, lane);
                float hb[4];
                #pragma unroll
                for (int r = 0; r < 4; ++r) {
                    hb[r] = tanhf(hsum[r] + ((const float*)&vbh0)[r]);
                    h0l[r] = hb[r];
                }
                agent_store64((u64*)(h0cur + (size_t)(m0 + lrow) * HH + nb),
                              pack4(hb[0], hb[1], hb[2], hb[3]));
                if (t + 1 < TT) {
                    float sb[4];
                    #pragma unroll
                    for (int r = 0; r < 4; ++r) {
                        float al = 1.f / (1.f + __expf(-(asum[r] + ((const float*)&vba0)[r])));
                        sb[r] = al * hb[r] + (1.f - al) * s0l[r];
                        s0l[r] = sb[r];
                    }
                    agent_store64((u64*)(s0nxt + (size_t)(m0 + lrow) * HH + nb),
                                  pack4(sb[0], sb[1], sb[2], sb[3]));
                }
            }
            flag_set(fB, wgl, (unsigned)(t + 1), tid);

            if (t + 1 < TT) {
                // fill the fB-wait window with next x partials
                #pragma unroll
                for (int nt = 0; nt < 4; ++nt) pBx[nt] = zf;
                mmx4(pBx, xbase + (size_t)(t + 1) * DD, wWih0, n0, lrow, wv, lkg);
                if (t + 2 < TT) {
                    #pragma unroll
                    for (int nt = 0; nt < 4; ++nt) pAx[nt] = zf;
                    mmx4(pAx, xbase + (size_t)(t + 2) * DD, wWax0, n0, lrow, wv, lkg);
                }
                flag_wait(fB, (unsigned)(t + 1), tid);   // all s0(t+1) published
                load_frags(frags, s0nxt, arow, wv, lkg);
                // s0 parity WAR: B(t+1) overwrites s0[t&1]=s0(t-1)... writer
                // passed fB(t+1): all WGs finished B(t) which consumed s0(t-1)
                // frags loaded before their fB(t) set. Safe.
            }
        }
        if (own) {
            const size_t o = (size_t)(m0 + lrow) * HH + nb;
            *(float4*)(out + HIDB + o) = make_float4(h0l[0], h0l[1], h0l[2], h0l[3]);
            *(float4*)(out + SMOB + o) = make_float4(s0l[0], s0l[1], s0l[2], s0l[3]);
        }
    } else {
        // ================== layer-1 pool: C+D (1 serial exchange/step) =======
        float4 vba1 = {0,0,0,0}, vbh1 = {0,0,0,0};
        if (own) { vba1 = *(const float4*)(ba1 + nb); vbh1 = *(const float4*)(bh1 + nb); }
        float h1l[4] = {0,0,0,0}, s1l[4] = {0,0,0,0};
        f32x4 pC1[4];
        #pragma unroll
        for (int nt = 0; nt < 4; ++nt) pC1[nt] = zf;   // Uas1 s1(-1) = 0

        for (int t = 0; t < TT; ++t) {
            u16* h0cur = h0r + (size_t)(t & (RING - 1)) * SPAN;
            u16* s1cur = s1b + (t & 1) * SPAN;

            // s1 parity WAR: C(t) overwrites s1(t-2); D(t-2) readers done iff
            // fD >= t-1 (fD set after D's fs1 loads+mfma).
            if (t >= 2) flag_wait(fD, (unsigned)(t - 1), tid);

            // h0(t) from ring; producer runs ahead -> usually pre-satisfied.
            flag_wait(fB, (unsigned)(t + 1), tid);
            short8 fh[4];
            load_frags(fh, h0cur, arow, wv, lkg);

            // ---- C: alpha1(t), s1(t) publish ----
            f32x4 c[4];
            #pragma unroll
            for (int nt = 0; nt < 4; ++nt) c[nt] = pC1[nt];
            mm4(c, fh, wWax1, n0, lrow, wv, lkg);
            red_put(red, c, wv, lane);
            __syncthreads();
            if (own) {
                f32x4 csum = red_get(red, wv, lane);
                float sb[4];
                #pragma unroll
                for (int r = 0; r < 4; ++r) {
                    float al = 1.f / (1.f + __expf(-(csum[r] + ((const float*)&vba1)[r])));
                    sb[r] = al * h1l[r] + (1.f - al) * s1l[r];
                    s1l[r] = sb[r];
                }
                agent_store64((u64*)(s1cur + (size_t)(m0 + lrow) * HH + nb),
                              pack4(sb[0], sb[1], sb[2], sb[3]));
            }
            flag_set(fC, wgl, (unsigned)(t + 1), tid);

            // hide pD1 = Wih1 h0 inside the fC exchange window (fh in regs)
            f32x4 pD1[4];
            #pragma unroll
            for (int nt = 0; nt < 4; ++nt) pD1[nt] = zf;
            mm4(pD1, fh, wWih1, n0, lrow, wv, lkg);

            // ---- D: wait s1(t); h1(t); pC1 for C(t+1) ----
            flag_wait(fC, (unsigned)(t + 1), tid);
            short8 fs1[4];
            load_frags(fs1, s1cur, arow, wv, lkg);
            mm4(pD1, fs1, wWhh1, n0, lrow, wv, lkg);
            #pragma unroll
            for (int nt = 0; nt < 4; ++nt) pC1[nt] = zf;
            mm4(pC1, fs1, wUas1, n0, lrow, wv, lkg);
            red_put(red, pD1, wv, lane);
            __syncthreads();
            if (own) {
                f32x4 dsum = red_get(red, wv, lane);
                #pragma unroll
                for (int r = 0; r < 4; ++r)
                    h1l[r] = tanhf(dsum[r] + ((const float*)&vbh1)[r]);
            }
            flag_set(fD, wgl, (unsigned)(t + 1), tid);
        }
        if (own) {
            const size_t o = (size_t)(m0 + lrow) * HH + nb;
            *(float4*)(out + HIDB + SPAN + o) = make_float4(h1l[0], h1l[1], h1l[2], h1l[3]);
            *(float4*)(out + SMOB + SPAN + o) = make_float4(s1l[0], s1l[1], s1l[2], s1l[3]);

            const float4 w4 = *(const float4*)(fcW + nb);
            float v = h1l[0] * w4.x + h1l[1] * w4.y + h1l[2] * w4.z + h1l[3] * w4.w;
            v += __shfl_xor(v, 16);
            v += __shfl_xor(v, 32);
            if (lane < 16) {
                if (ngg == 0 && wv == 0) v += fcb[0];
                atomicAdd(out + m0 + lane, v);
            }
        }
    }
}

extern "C" void kernel_launch(void* const* d_in, const int* in_sizes, int n_in,
                              void* d_out, int out_size, void* d_ws, size_t ws_size,
                              hipStream_t stream)
{
    const float* x    = (const float*)d_in[0];
    const float* Wax0 = (const float*)d_in[1];
    const float* Uas0 = (const float*)d_in[2];
    const float* ba0  = (const float*)d_in[3];
    const float* Wih0 = (const float*)d_in[4];
    const float* Whh0 = (const float*)d_in[5];
    const float* bh0  = (const float*)d_in[6];
    const float* Wax1 = (const float*)d_in[7];
    const float* Uas1 = (const float*)d_in[8];
    const float* ba1  = (const float*)d_in[9];
    const float* Wih1 = (const float*)d_in[10];
    const float* Whh1 = (const float*)d_in[11];
    const float* bh1  = (const float*)d_in[12];
    const float* fcW  = (const float*)d_in[13];
    const float* fcb  = (const float*)d_in[14];
    float* out = (float*)d_out;

    char* ws = (char*)d_ws;
    u16* s0b = (u16*)(ws + S0_OFF);
    u16* s1b = (u16*)(ws + S1_OFF);
    u16* h0r = (u16*)(ws + H0_OFF);
    unsigned* flags = (unsigned*)(ws + FL_OFF);
    u16* wbase = (u16*)(ws + W_OFF);
    u16* wUas0 = wbase + 0 * 1048576;
    u16* wWhh0 = wbase + 1 * 1048576;
    u16* wWax1 = wbase + 2 * 1048576;
    u16* wUas1 = wbase + 3 * 1048576;
    u16* wWih1 = wbase + 4 * 1048576;
    u16* wWhh1 = wbase + 5 * 1048576;
    u16* wWax0 = wbase + 6 * 1048576;
    u16* wWih0 = wbase + 6 * 1048576 + 262144;

    // zero states + ring + flags + output (out accumulated via atomics)
    hipMemsetAsync(d_ws, 0, W_OFF, stream);
    hipMemsetAsync(d_out, 0, (size_t)out_size * sizeof(float), stream);

    conv_weights<<<dim3(1024), dim3(256), 0, stream>>>(
        Uas0, Whh0, Wax1, Uas1, Wih1, Whh1, Wax0, Wih0, wbase);

    alphat_mfma<<<dim3(256), dim3(NTHR), 0, stream>>>(
        x, wUas0, wWhh0, wWax1, wUas1, wWih1, wWhh1, wWax0, wWih0,
        ba0, bh0, ba1, bh1, fcW, fcb, out, s0b, s1b, h0r, flags);
}